// Round 1
// baseline (7687.104 us; speedup 1.0000x reference)
//
#include <hip/hip_runtime.h>
#include <hip/hip_bf16.h>
#include <math.h>

// ---------------------------------------------------------------------------
// GATGNN forward, fp32. Stages:
//   h = x@Wn + bn                      [N,64]
//   ea = leaky_relu(eattr@We + be)     [E,64]
//   3x AGATConv layer:
//     per-edge: m = ea@Wbot; ui = h[dst]@Wtop; uj = h[src]@Wtop
//               ti = sp(ui+m); tj = sp(uj+m)
//               a1 = sp(dot(ti,att[:64]) + dot(tj,att[64:]))
//     alpha = sp(BN_E(a1)); seg-softmax over dst; agg = seg-sum(tj*alpha)
//     h = sp(BN_N(agg))      (conv_bias cancels in BN: gamma=1, beta=0)
//   comp attention + seg-softmax over (sorted) batch + pool + fc
// ---------------------------------------------------------------------------

__device__ __forceinline__ float sp_f(float x) {
  return x > 20.0f ? x : log1pf(expf(x));
}

// out[R,64] = act(in[R,K] @ W[K,64] + b);  ACT: 0=none, 1=leaky_relu(0.2)
template<int K, int ACT>
__global__ __launch_bounds__(256) void k_embed(
    const float* __restrict__ in, const float* __restrict__ W,
    const float* __restrict__ b, float* __restrict__ out, int R)
{
  __shared__ float Ws[K * 64];
  for (int i = threadIdx.x; i < K * 64; i += 256) Ws[i] = W[i];
  __syncthreads();
  const int c = threadIdx.x & 63;
  const int r = threadIdx.x >> 6;
  const float bias = b[c];
  for (long row = (long)blockIdx.x * 4 + r; row < R; row += (long)gridDim.x * 4) {
    const float* ip = in + row * K;
    float acc = bias;
    #pragma unroll 8
    for (int k = 0; k < K; ++k) acc = fmaf(ip[k], Ws[k * 64 + c], acc);
    if (ACT == 1) acc = acc >= 0.0f ? acc : 0.2f * acc;
    out[row * 64 + c] = acc;
  }
}

// one wave per edge: compute raw attention logit a1[e] = sp(s_i + s_j)
__global__ __launch_bounds__(256) void k_edge(
    const float* __restrict__ h, const float* __restrict__ ea,
    const int* __restrict__ eidx, const float* __restrict__ convW,
    const float* __restrict__ catt, float* __restrict__ a1, int E)
{
  __shared__ float Ws[128 * 64];
  __shared__ float atts[128];
  for (int i = threadIdx.x; i < 128 * 64; i += 256) Ws[i] = convW[i];
  if (threadIdx.x < 128) atts[threadIdx.x] = catt[threadIdx.x];
  __syncthreads();
  const int t = threadIdx.x & 63;
  const int wid = threadIdx.x >> 6;
  const int step = gridDim.x * 4;
  for (int e = blockIdx.x * 4 + wid; e < E; e += step) {
    const int s = eidx[e];
    const int d = eidx[E + e];
    const float hd = h[(long)d * 64 + t];
    const float hs = h[(long)s * 64 + t];
    const float ev = ea[(long)e * 64 + t];
    float ui = 0.f, uj = 0.f, m = 0.f;
    #pragma unroll
    for (int k = 0; k < 64; ++k) {
      const float bhd = __shfl(hd, k);
      const float bhs = __shfl(hs, k);
      const float bev = __shfl(ev, k);
      const float wt = Ws[k * 64 + t];
      const float wb = Ws[(64 + k) * 64 + t];
      ui = fmaf(bhd, wt, ui);
      uj = fmaf(bhs, wt, uj);
      m  = fmaf(bev, wb, m);
    }
    const float ti = sp_f(ui + m);
    const float tj = sp_f(uj + m);
    float part = ti * atts[t] + tj * atts[64 + t];
    #pragma unroll
    for (int off = 32; off; off >>= 1) part += __shfl_xor(part, off);
    if (t == 0) a1[e] = sp_f(part);
  }
}

// sum & sumsq of a[0..n) into stats[0..1] (pre-zeroed)
__global__ __launch_bounds__(256) void k_reduce1(
    const float* __restrict__ a, int n, float* __restrict__ stats)
{
  float s = 0.f, s2 = 0.f;
  for (int i = blockIdx.x * 256 + threadIdx.x; i < n; i += gridDim.x * 256) {
    const float v = a[i];
    s += v; s2 += v * v;
  }
  #pragma unroll
  for (int off = 32; off; off >>= 1) { s += __shfl_xor(s, off); s2 += __shfl_xor(s2, off); }
  __shared__ float ls[4], ls2[4];
  const int wid = threadIdx.x >> 6;
  if ((threadIdx.x & 63) == 0) { ls[wid] = s; ls2[wid] = s2; }
  __syncthreads();
  if (threadIdx.x == 0) {
    float S = ls[0] + ls[1] + ls[2] + ls[3];
    float S2 = ls2[0] + ls2[1] + ls2[2] + ls2[3];
    atomicAdd(&stats[0], S);
    atomicAdd(&stats[1], S2);
  }
}

// alpha2 = sp((a1 - mean)*rsqrt(var+eps)); scatter-max to nmax[dst] (values > 0)
__global__ __launch_bounds__(256) void k_alpha_bn(
    float* __restrict__ aE, const int* __restrict__ dstp, int E,
    const float* __restrict__ stats, float invE, unsigned int* __restrict__ nmax)
{
  const float mean = stats[0] * invE;
  const float var = stats[1] * invE - mean * mean;
  const float scl = rsqrtf(var + 1e-5f);
  for (int i = blockIdx.x * 256 + threadIdx.x; i < E; i += gridDim.x * 256) {
    const float v = sp_f((aE[i] - mean) * scl);
    aE[i] = v;
    atomicMax(&nmax[dstp[i]], __float_as_uint(v));  // v > 0: uint cmp == float cmp
  }
}

// ew = exp(alpha2 - max[dst]); scatter-add to nsum[dst]
__global__ __launch_bounds__(256) void k_expsum(
    float* __restrict__ aE, const int* __restrict__ dstp, int E,
    const unsigned int* __restrict__ nmax, float* __restrict__ nsum)
{
  for (int i = blockIdx.x * 256 + threadIdx.x; i < E; i += gridDim.x * 256) {
    const float mx = __uint_as_float(nmax[dstp[i]]);
    const float w = expf(aE[i] - mx);
    aE[i] = w;
    atomicAdd(&nsum[dstp[i]], w);
  }
}

// recompute tj per edge, scatter-add tj * (ew/nsum[dst]) into agg[dst]
__global__ __launch_bounds__(256) void k_agg(
    const float* __restrict__ h, const float* __restrict__ ea,
    const int* __restrict__ eidx, const float* __restrict__ convW,
    const float* __restrict__ ew, const float* __restrict__ nsum,
    float* __restrict__ agg, int E)
{
  __shared__ float Ws[128 * 64];
  for (int i = threadIdx.x; i < 128 * 64; i += 256) Ws[i] = convW[i];
  __syncthreads();
  const int t = threadIdx.x & 63;
  const int wid = threadIdx.x >> 6;
  const int step = gridDim.x * 4;
  for (int e = blockIdx.x * 4 + wid; e < E; e += step) {
    const int s = eidx[e];
    const int d = eidx[E + e];
    const float hs = h[(long)s * 64 + t];
    const float ev = ea[(long)e * 64 + t];
    float uj = 0.f, m = 0.f;
    #pragma unroll
    for (int k = 0; k < 64; ++k) {
      const float bhs = __shfl(hs, k);
      const float bev = __shfl(ev, k);
      uj = fmaf(bhs, Ws[k * 64 + t], uj);
      m  = fmaf(bev, Ws[(64 + k) * 64 + t], m);
    }
    const float tj = sp_f(uj + m);
    const float w = ew[e] / nsum[d];
    atomicAdd(&agg[(long)d * 64 + t], tj * w);
  }
}

// per-column sum & sumsq of agg[N,64] into cs[0..63], cs[64..127] (pre-zeroed)
__global__ __launch_bounds__(256) void k_colstats(
    const float* __restrict__ agg, int N, float* __restrict__ cs)
{
  const int c = threadIdx.x & 63;
  const int r = threadIdx.x >> 6;
  float s = 0.f, s2 = 0.f;
  for (long n = (long)blockIdx.x * 4 + r; n < N; n += (long)gridDim.x * 4) {
    const float v = agg[n * 64 + c];
    s += v; s2 += v * v;
  }
  __shared__ float b1[256], b2[256];
  b1[threadIdx.x] = s; b2[threadIdx.x] = s2;
  __syncthreads();
  if (threadIdx.x < 64) {
    const float S = b1[c] + b1[64 + c] + b1[128 + c] + b1[192 + c];
    const float S2 = b2[c] + b2[64 + c] + b2[128 + c] + b2[192 + c];
    atomicAdd(&cs[c], S);
    atomicAdd(&cs[64 + c], S2);
  }
}

// h = sp((agg - mean_c) * rsqrt(var_c + eps))
__global__ __launch_bounds__(256) void k_hnew(
    const float* __restrict__ agg, const float* __restrict__ cs,
    float invN, float* __restrict__ h, int N)
{
  const long total = (long)N * 64;
  for (long i = (long)blockIdx.x * 256 + threadIdx.x; i < total; i += (long)gridDim.x * 256) {
    const int c = (int)(i & 63);
    const float mean = cs[c] * invN;
    const float var = cs[64 + c] * invN - mean * mean;
    h[i] = sp_f((agg[i] - mean) * rsqrtf(var + 1e-5f));
  }
}

// composition attention score a[n] = sp(concat(h,gf)@Wc + bc) @ attW + attb
__global__ __launch_bounds__(256) void k_comp(
    const float* __restrict__ h, const float* __restrict__ gf,
    const int* __restrict__ batch, const float* __restrict__ Wc,
    const float* __restrict__ bc, const float* __restrict__ aw,
    const float* __restrict__ ab, float* __restrict__ aN, int N)
{
  __shared__ float Wcs[167 * 32];
  __shared__ float aws[32];
  __shared__ float bcs[32];
  for (int i = threadIdx.x; i < 167 * 32; i += 256) Wcs[i] = Wc[i];
  if (threadIdx.x < 32) { aws[threadIdx.x] = aw[threadIdx.x]; bcs[threadIdx.x] = bc[threadIdx.x]; }
  __syncthreads();
  const int t = threadIdx.x & 63;
  const int wid = threadIdx.x >> 6;
  const int col = t & 31;
  const float ab0 = ab[0];
  const int step = gridDim.x * 4;
  for (int n = blockIdx.x * 4 + wid; n < N; n += step) {
    const int g = batch[n];
    const float hq = h[(long)n * 64 + t];
    const float g1 = gf[(long)g * 103 + t];                       // q[64+t], t<64
    const float g2 = (t < 39) ? gf[(long)g * 103 + 64 + t] : 0.f; // q[128+t], t<39
    float acc = bcs[col];
    #pragma unroll 8
    for (int k = 0; k < 64; ++k) acc = fmaf(__shfl(hq, k), Wcs[k * 32 + col], acc);
    #pragma unroll 8
    for (int k = 0; k < 64; ++k) acc = fmaf(__shfl(g1, k), Wcs[(64 + k) * 32 + col], acc);
    #pragma unroll
    for (int k = 0; k < 39; ++k) acc = fmaf(__shfl(g2, k), Wcs[(128 + k) * 32 + col], acc);
    float val = sp_f(acc) * aws[col];
    #pragma unroll
    for (int off = 16; off; off >>= 1) val += __shfl_xor(val, off);
    if (t == 0) aN[n] = val + ab0;
  }
}

// one 64-thread block per graph: seg-softmax over sorted batch + pool + fc
__global__ __launch_bounds__(64) void k_pool(
    const float* __restrict__ h, const float* __restrict__ aN,
    const int* __restrict__ batch, const float* __restrict__ fcW,
    const float* __restrict__ fcb, float* __restrict__ out, int N, int G)
{
  const int g = blockIdx.x;
  const int t = threadIdx.x;
  int lo = 0, hi = N;
  while (lo < hi) { int mid = (lo + hi) >> 1; if (batch[mid] < g) lo = mid + 1; else hi = mid; }
  const int s = lo;
  hi = N;
  while (lo < hi) { int mid = (lo + hi) >> 1; if (batch[mid] < g + 1) lo = mid + 1; else hi = mid; }
  const int e2 = lo;
  if (s >= e2) { if (t == 0) out[g] = fcb[0]; return; }
  float mx = -1e30f;
  for (int i = s + t; i < e2; i += 64) mx = fmaxf(mx, aN[i]);
  #pragma unroll
  for (int off = 32; off; off >>= 1) mx = fmaxf(mx, __shfl_xor(mx, off));
  float se = 0.f;
  for (int i = s + t; i < e2; i += 64) se += expf(aN[i] - mx);
  #pragma unroll
  for (int off = 32; off; off >>= 1) se += __shfl_xor(se, off);
  float acc = 0.f;
  for (int n = s; n < e2; ++n) {
    const float w = expf(aN[n] - mx);
    acc = fmaf(h[(long)n * 64 + t], w, acc);
  }
  float part = (acc / se) * fcW[t];
  #pragma unroll
  for (int off = 32; off; off >>= 1) part += __shfl_xor(part, off);
  if (t == 0) out[g] = part + fcb[0];
}

extern "C" void kernel_launch(void* const* d_in, const int* in_sizes, int n_in,
                              void* d_out, int out_size, void* d_ws, size_t ws_size,
                              hipStream_t stream)
{
  const float* x     = (const float*)d_in[0];
  const int*   eidx  = (const int*)  d_in[1];
  const float* eattr = (const float*)d_in[2];
  const int*   batch = (const int*)  d_in[3];
  const float* gfeat = (const float*)d_in[4];
  const float* embnW = (const float*)d_in[5];
  const float* embnb = (const float*)d_in[6];
  const float* embeW = (const float*)d_in[7];
  const float* embeb = (const float*)d_in[8];
  const float* convW = (const float*)d_in[9];
  const float* convA = (const float*)d_in[10];
  // d_in[11] = conv_bias: cancels exactly in training-mode BatchNorm (gamma=1, beta=0)
  const float* compW = (const float*)d_in[12];
  const float* compb = (const float*)d_in[13];
  const float* attW  = (const float*)d_in[14];
  const float* attb  = (const float*)d_in[15];
  const float* fcW   = (const float*)d_in[16];
  const float* fcb   = (const float*)d_in[17];
  float* out = (float*)d_out;

  const int N = in_sizes[0] / 92;
  const int E = in_sizes[1] / 2;
  const int G = in_sizes[4] / 103;

  // workspace layout (fp32), ~130 MB total
  float* h  = (float*)d_ws;                 // N*64
  float* ea = h + (size_t)N * 64;           // E*64
  float* aE = ea + (size_t)E * 64;          // E     (a1 -> alpha2 -> ew, in place)
  float* zr = aE + E;                       // zeroed region start:
  float* stats = zr;                        //   [0..1]   sum/sumsq of a1   (pad 64)
  float* cs    = zr + 64;                   //   [0..127] col sum/sumsq     (pad 192)
  unsigned int* nmax = (unsigned int*)(zr + 256);  // N
  float* nsum  = zr + 256 + (size_t)N;      // N
  float* agg   = zr + 256 + 2 * (size_t)N;  // N*64
  float* aN    = agg + (size_t)N * 64;      // N (outside zeroed region)
  const size_t zero_bytes = (256 + 2 * (size_t)N + (size_t)N * 64) * sizeof(float);

  k_embed<92, 0><<<4096, 256, 0, stream>>>(x, embnW, embnb, h, N);
  k_embed<41, 1><<<8192, 256, 0, stream>>>(eattr, embeW, embeb, ea, E);

  for (int l = 0; l < 3; ++l) {
    const float* Wl = convW + (size_t)l * 128 * 64;
    const float* Al = convA + (size_t)l * 128;
    k_edge<<<8192, 256, 0, stream>>>(h, ea, eidx, Wl, Al, aE, E);
    hipMemsetAsync(zr, 0, zero_bytes, stream);
    k_reduce1<<<1024, 256, 0, stream>>>(aE, E, stats);
    k_alpha_bn<<<2048, 256, 0, stream>>>(aE, eidx + E, E, stats, 1.0f / (float)E, nmax);
    k_expsum<<<2048, 256, 0, stream>>>(aE, eidx + E, E, nmax, nsum);
    k_agg<<<8192, 256, 0, stream>>>(h, ea, eidx, Wl, aE, nsum, agg, E);
    k_colstats<<<1024, 256, 0, stream>>>(agg, N, cs);
    k_hnew<<<2048, 256, 0, stream>>>(agg, cs, 1.0f / (float)N, h, N);
  }

  k_comp<<<4096, 256, 0, stream>>>(h, gfeat, batch, compW, compb, attW, attb, aN, N);
  k_pool<<<G, 64, 0, stream>>>(h, aN, batch, fcW, fcb, out, N, G);

  (void)n_in; (void)out_size; (void)ws_size;
}

// Round 2
// 2792.665 us; speedup vs baseline: 2.7526x; 2.7526x over previous
//
#include <hip/hip_runtime.h>
#include <hip/hip_bf16.h>
#include <math.h>

// ---------------------------------------------------------------------------
// GATGNN forward, restructured:
//   h = x@Wn + bn; ea = leaky_relu(eattr@We + be)
//   per layer:
//     P = h@Wtop (node proj), M = ea@Wbot (edge GEMM)
//     pass A (per edge): ti=sp(P[dst]+M), tj=sp(P[src]+M); M<-tj (in place);
//                        a1 = sp(dot(ti,att_i)+dot(tj,att_j))
//     BN(a1) -> seg-softmax over dst -> pass B: agg[dst] += tj*w
//     h = sp(BN(agg))          (conv_bias cancels in BN)
//   comp attention + seg-softmax over sorted batch + pool + fc
// Storage of ea / M degrades fp32->bf16 adaptively to fit ws_size.
// ---------------------------------------------------------------------------

typedef __hip_bfloat16 bf16;

__device__ __forceinline__ float sp_f(float x) {
  return x > 20.0f ? x : log1pf(expf(x));
}
template<typename T> __device__ __forceinline__ float ldf(const T* p);
template<> __device__ __forceinline__ float ldf<float>(const float* p) { return *p; }
template<> __device__ __forceinline__ float ldf<bf16>(const bf16* p) { return __bfloat162float(*p); }
template<typename T> __device__ __forceinline__ void stf(T* p, float v);
template<> __device__ __forceinline__ void stf<float>(float* p, float v) { *p = v; }
template<> __device__ __forceinline__ void stf<bf16>(bf16* p, float v) { *p = __float2bfloat16(v); }

// out[R,64] = act(in[R,K] @ W[K,64] (+ b));  ACT: 0=none, 1=leaky_relu(0.2)
template<int K, int ACT, int BIAS, typename IT, typename OT>
__global__ __launch_bounds__(256) void k_gemm64(
    const IT* __restrict__ in, const float* __restrict__ W,
    const float* __restrict__ b, OT* __restrict__ out, int R)
{
  __shared__ float Ws[K * 64];
  for (int i = threadIdx.x; i < K * 64; i += 256) Ws[i] = W[i];
  __syncthreads();
  const int c = threadIdx.x & 63;
  const int r = threadIdx.x >> 6;
  float bias = 0.0f;
  if (BIAS) bias = b[c];
  for (long row = (long)blockIdx.x * 4 + r; row < R; row += (long)gridDim.x * 4) {
    const IT* ip = in + row * K;
    float acc = bias;
    #pragma unroll 8
    for (int k = 0; k < K; ++k) acc = fmaf(ldf(&ip[k]), Ws[k * 64 + c], acc);
    if (ACT == 1) acc = acc >= 0.0f ? acc : 0.2f * acc;
    stf(&out[row * 64 + c], acc);
  }
}

// pass A: one wave per edge. ti=sp(P[dst]+M), tj=sp(P[src]+M); M <- tj;
// a1[e] = sp(ti.att_i + tj.att_j)
template<typename MT>
__global__ __launch_bounds__(256) void k_edgeA(
    const float* __restrict__ P, MT* __restrict__ M,
    const int* __restrict__ eidx, const float* __restrict__ catt,
    float* __restrict__ a1, int E)
{
  __shared__ float atts[128];
  if (threadIdx.x < 128) atts[threadIdx.x] = catt[threadIdx.x];
  __syncthreads();
  const int t = threadIdx.x & 63;
  const int wid = threadIdx.x >> 6;
  const long step = (long)gridDim.x * 4;
  for (long e = (long)blockIdx.x * 4 + wid; e < E; e += step) {
    const int s = eidx[e];
    const int d = eidx[E + e];
    const float m = ldf(&M[e * 64 + t]);
    const float ti = sp_f(P[(long)d * 64 + t] + m);
    const float tj = sp_f(P[(long)s * 64 + t] + m);
    stf(&M[e * 64 + t], tj);
    float part = ti * atts[t] + tj * atts[64 + t];
    #pragma unroll
    for (int off = 32; off; off >>= 1) part += __shfl_xor(part, off);
    if (t == 0) a1[e] = sp_f(part);
  }
}

// pass B: agg[dst] += tj * (ew[e]/nsum[dst])
template<typename MT>
__global__ __launch_bounds__(256) void k_edgeB(
    const MT* __restrict__ M, const int* __restrict__ dstp,
    const float* __restrict__ ew, const float* __restrict__ nsum,
    float* __restrict__ agg, int E)
{
  const int t = threadIdx.x & 63;
  const int wid = threadIdx.x >> 6;
  const long step = (long)gridDim.x * 4;
  for (long e = (long)blockIdx.x * 4 + wid; e < E; e += step) {
    const int d = dstp[e];
    const float w = ew[e] / nsum[d];
    const float tj = ldf(&M[e * 64 + t]);
    atomicAdd(&agg[(long)d * 64 + t], tj * w);
  }
}

// sum & sumsq of a[0..n) into stats[0..1] (pre-zeroed)
__global__ __launch_bounds__(256) void k_reduce1(
    const float* __restrict__ a, int n, float* __restrict__ stats)
{
  float s = 0.f, s2 = 0.f;
  for (int i = blockIdx.x * 256 + threadIdx.x; i < n; i += gridDim.x * 256) {
    const float v = a[i];
    s += v; s2 += v * v;
  }
  #pragma unroll
  for (int off = 32; off; off >>= 1) { s += __shfl_xor(s, off); s2 += __shfl_xor(s2, off); }
  __shared__ float ls[4], ls2[4];
  const int wid = threadIdx.x >> 6;
  if ((threadIdx.x & 63) == 0) { ls[wid] = s; ls2[wid] = s2; }
  __syncthreads();
  if (threadIdx.x == 0) {
    atomicAdd(&stats[0], ls[0] + ls[1] + ls[2] + ls[3]);
    atomicAdd(&stats[1], ls2[0] + ls2[1] + ls2[2] + ls2[3]);
  }
}

// alpha2 = sp((a1 - mean)*rsqrt(var+eps)); scatter-max to nmax[dst] (values > 0)
__global__ __launch_bounds__(256) void k_alpha_bn(
    float* __restrict__ aE, const int* __restrict__ dstp, int E,
    const float* __restrict__ stats, float invE, unsigned int* __restrict__ nmax)
{
  const float mean = stats[0] * invE;
  const float var = stats[1] * invE - mean * mean;
  const float scl = rsqrtf(var + 1e-5f);
  for (int i = blockIdx.x * 256 + threadIdx.x; i < E; i += gridDim.x * 256) {
    const float v = sp_f((aE[i] - mean) * scl);
    aE[i] = v;
    atomicMax(&nmax[dstp[i]], __float_as_uint(v));  // v > 0: uint cmp == float cmp
  }
}

// ew = exp(alpha2 - max[dst]); scatter-add to nsum[dst]
__global__ __launch_bounds__(256) void k_expsum(
    float* __restrict__ aE, const int* __restrict__ dstp, int E,
    const unsigned int* __restrict__ nmax, float* __restrict__ nsum)
{
  for (int i = blockIdx.x * 256 + threadIdx.x; i < E; i += gridDim.x * 256) {
    const float mx = __uint_as_float(nmax[dstp[i]]);
    const float w = expf(aE[i] - mx);
    aE[i] = w;
    atomicAdd(&nsum[dstp[i]], w);
  }
}

// per-column sum & sumsq of agg[N,64] into cs[0..63], cs[64..127] (pre-zeroed)
__global__ __launch_bounds__(256) void k_colstats(
    const float* __restrict__ agg, int N, float* __restrict__ cs)
{
  const int c = threadIdx.x & 63;
  const int r = threadIdx.x >> 6;
  float s = 0.f, s2 = 0.f;
  for (long n = (long)blockIdx.x * 4 + r; n < N; n += (long)gridDim.x * 4) {
    const float v = agg[n * 64 + c];
    s += v; s2 += v * v;
  }
  __shared__ float b1[256], b2[256];
  b1[threadIdx.x] = s; b2[threadIdx.x] = s2;
  __syncthreads();
  if (threadIdx.x < 64) {
    atomicAdd(&cs[c], b1[c] + b1[64 + c] + b1[128 + c] + b1[192 + c]);
    atomicAdd(&cs[64 + c], b2[c] + b2[64 + c] + b2[128 + c] + b2[192 + c]);
  }
}

// h = sp((agg - mean_c) * rsqrt(var_c + eps))
__global__ __launch_bounds__(256) void k_hnew(
    const float* __restrict__ agg, const float* __restrict__ cs,
    float invN, float* __restrict__ h, int N)
{
  const long total = (long)N * 64;
  for (long i = (long)blockIdx.x * 256 + threadIdx.x; i < total; i += (long)gridDim.x * 256) {
    const int c = (int)(i & 63);
    const float mean = cs[c] * invN;
    const float var = cs[64 + c] * invN - mean * mean;
    h[i] = sp_f((agg[i] - mean) * rsqrtf(var + 1e-5f));
  }
}

// composition attention score a[n] = sp(concat(h,gf)@Wc + bc) @ attW + attb
__global__ __launch_bounds__(256) void k_comp(
    const float* __restrict__ h, const float* __restrict__ gf,
    const int* __restrict__ batch, const float* __restrict__ Wc,
    const float* __restrict__ bc, const float* __restrict__ aw,
    const float* __restrict__ ab, float* __restrict__ aN, int N)
{
  __shared__ float Wcs[167 * 32];
  __shared__ float aws[32];
  __shared__ float bcs[32];
  for (int i = threadIdx.x; i < 167 * 32; i += 256) Wcs[i] = Wc[i];
  if (threadIdx.x < 32) { aws[threadIdx.x] = aw[threadIdx.x]; bcs[threadIdx.x] = bc[threadIdx.x]; }
  __syncthreads();
  const int t = threadIdx.x & 63;
  const int wid = threadIdx.x >> 6;
  const int col = t & 31;
  const float ab0 = ab[0];
  const int step = gridDim.x * 4;
  for (int n = blockIdx.x * 4 + wid; n < N; n += step) {
    const int g = batch[n];
    const float hq = h[(long)n * 64 + t];
    const float g1 = gf[(long)g * 103 + t];
    const float g2 = (t < 39) ? gf[(long)g * 103 + 64 + t] : 0.f;
    float acc = bcs[col];
    #pragma unroll 8
    for (int k = 0; k < 64; ++k) acc = fmaf(__shfl(hq, k), Wcs[k * 32 + col], acc);
    #pragma unroll 8
    for (int k = 0; k < 64; ++k) acc = fmaf(__shfl(g1, k), Wcs[(64 + k) * 32 + col], acc);
    #pragma unroll
    for (int k = 0; k < 39; ++k) acc = fmaf(__shfl(g2, k), Wcs[(128 + k) * 32 + col], acc);
    float val = sp_f(acc) * aws[col];
    #pragma unroll
    for (int off = 16; off; off >>= 1) val += __shfl_xor(val, off);
    if (t == 0) aN[n] = val + ab0;
  }
}

// one 64-thread block per graph: seg-softmax over sorted batch + pool + fc
__global__ __launch_bounds__(64) void k_pool(
    const float* __restrict__ h, const float* __restrict__ aN,
    const int* __restrict__ batch, const float* __restrict__ fcW,
    const float* __restrict__ fcb, float* __restrict__ out, int N, int G)
{
  const int g = blockIdx.x;
  const int t = threadIdx.x;
  int lo = 0, hi = N;
  while (lo < hi) { int mid = (lo + hi) >> 1; if (batch[mid] < g) lo = mid + 1; else hi = mid; }
  const int s = lo;
  hi = N;
  while (lo < hi) { int mid = (lo + hi) >> 1; if (batch[mid] < g + 1) lo = mid + 1; else hi = mid; }
  const int e2 = lo;
  if (s >= e2) { if (t == 0) out[g] = fcb[0]; return; }
  float mx = -1e30f;
  for (int i = s + t; i < e2; i += 64) mx = fmaxf(mx, aN[i]);
  #pragma unroll
  for (int off = 32; off; off >>= 1) mx = fmaxf(mx, __shfl_xor(mx, off));
  float se = 0.f;
  for (int i = s + t; i < e2; i += 64) se += expf(aN[i] - mx);
  #pragma unroll
  for (int off = 32; off; off >>= 1) se += __shfl_xor(se, off);
  float acc = 0.f;
  for (int n = s; n < e2; ++n) {
    const float w = expf(aN[n] - mx);
    acc = fmaf(h[(long)n * 64 + t], w, acc);
  }
  float part = (acc / se) * fcW[t];
  #pragma unroll
  for (int off = 32; off; off >>= 1) part += __shfl_xor(part, off);
  if (t == 0) out[g] = part + fcb[0];
}

template<typename EAT, typename MT>
static void run_all(void* const* d_in, int N, int E, int G,
                    float* out, void* d_ws, hipStream_t stream)
{
  const float* x     = (const float*)d_in[0];
  const int*   eidx  = (const int*)  d_in[1];
  const float* eattr = (const float*)d_in[2];
  const int*   batch = (const int*)  d_in[3];
  const float* gfeat = (const float*)d_in[4];
  const float* embnW = (const float*)d_in[5];
  const float* embnb = (const float*)d_in[6];
  const float* embeW = (const float*)d_in[7];
  const float* embeb = (const float*)d_in[8];
  const float* convW = (const float*)d_in[9];
  const float* convA = (const float*)d_in[10];
  // d_in[11] = conv_bias: cancels exactly in training-mode BatchNorm
  const float* compW = (const float*)d_in[12];
  const float* compb = (const float*)d_in[13];
  const float* attW  = (const float*)d_in[14];
  const float* attb  = (const float*)d_in[15];
  const float* fcW   = (const float*)d_in[16];
  const float* fcb   = (const float*)d_in[17];

  // layout
  float* h     = (float*)d_ws;                    // N*64
  float* Pagg  = h + (size_t)N * 64;              // N*64: P (pass A), then agg
  float* aE    = Pagg + (size_t)N * 64;           // E
  float* stats = aE + E;                          // 256: [0..1] BN-E, [64..191] cs
  unsigned int* nmax = (unsigned int*)(stats + 256);  // N
  float* nsum  = stats + 256 + (size_t)N;         // N
  float* aN    = stats + 256 + 2 * (size_t)N;     // N
  char*  p     = (char*)(stats + 256 + 3 * (size_t)N);
  EAT* ea = (EAT*)p;  p += (size_t)E * 64 * sizeof(EAT);
  MT*  M  = (MT*)p;                               // M, then tj (in place)

  const int gE = (E + 3) / 4;
  const int gN = (N + 3) / 4;

  k_gemm64<92, 0, 1, float, float><<<gN, 256, 0, stream>>>(x, embnW, embnb, h, N);
  k_gemm64<41, 1, 1, float, EAT><<<gE, 256, 0, stream>>>(eattr, embeW, embeb, ea, E);

  for (int l = 0; l < 3; ++l) {
    const float* Wl = convW + (size_t)l * 128 * 64;
    const float* Al = convA + (size_t)l * 128;
    k_gemm64<64, 0, 0, float, float><<<gN, 256, 0, stream>>>(h, Wl, nullptr, Pagg, N);
    k_gemm64<64, 0, 0, EAT, MT><<<gE, 256, 0, stream>>>(ea, Wl + 64 * 64, nullptr, M, E);
    k_edgeA<MT><<<gE, 256, 0, stream>>>(Pagg, M, eidx, Al, aE, E);
    hipMemsetAsync(stats, 0, (256 + 2 * (size_t)N) * sizeof(float), stream);
    hipMemsetAsync(Pagg, 0, (size_t)N * 64 * sizeof(float), stream);
    k_reduce1<<<1024, 256, 0, stream>>>(aE, E, stats);
    k_alpha_bn<<<2048, 256, 0, stream>>>(aE, eidx + E, E, stats, 1.0f / (float)E, nmax);
    k_expsum<<<2048, 256, 0, stream>>>(aE, eidx + E, E, nmax, nsum);
    k_edgeB<MT><<<gE, 256, 0, stream>>>(M, eidx + E, aE, nsum, Pagg, E);
    k_colstats<<<1024, 256, 0, stream>>>(Pagg, N, stats + 64);
    k_hnew<<<2048, 256, 0, stream>>>(Pagg, stats + 64, 1.0f / (float)N, h, N);
  }

  k_comp<<<gN, 256, 0, stream>>>(h, gfeat, batch, compW, compb, attW, attb, aN, N);
  k_pool<<<G, 64, 0, stream>>>(h, aN, batch, fcW, fcb, out, N, G);
}

extern "C" void kernel_launch(void* const* d_in, const int* in_sizes, int n_in,
                              void* d_out, int out_size, void* d_ws, size_t ws_size,
                              hipStream_t stream)
{
  const int N = in_sizes[0] / 92;
  const int E = in_sizes[1] / 2;
  const int G = in_sizes[4] / 103;
  float* out = (float*)d_out;

  const size_t fixed = ((size_t)N * 64 * 2 + E + 256 + 3 * (size_t)N) * 4;
  const size_t planA = fixed + (size_t)E * 64 * (4 + 4);
  const size_t planB = fixed + (size_t)E * 64 * (4 + 2);

  if (ws_size >= planA)      run_all<float, float>(d_in, N, E, G, out, d_ws, stream);
  else if (ws_size >= planB) run_all<float, bf16>(d_in, N, E, G, out, d_ws, stream);
  else                       run_all<bf16, bf16>(d_in, N, E, G, out, d_ws, stream);

  (void)n_in; (void)out_size; (void)ws_size;
}

// Round 3
// 1652.095 us; speedup vs baseline: 4.6529x; 1.6904x over previous
//
#include <hip/hip_runtime.h>
#include <hip/hip_bf16.h>
#include <math.h>

// ---------------------------------------------------------------------------
// GATGNN forward, fp32 (ws_size >= 233 MB proven in round 2).
//   h = x@Wn + bn; ea = leaky_relu(eattr@We + be)
//   per layer:
//     P = h@Wtop                     (register-tiled GEMM)
//     fused: M = ea@Wbot; ti=sp(P[dst]+M), tj=sp(P[src]+M); M<-tj;
//            a1 = sp(dot(ti,att_i)+dot(tj,att_j))          (GEMM + epilogue)
//     BN(a1) -> seg-softmax over dst -> agg[dst] += tj*w
//     h = sp(BN(agg))                (conv_bias cancels in BN)
//   comp attention + seg-softmax over sorted batch + pool + fc
// ---------------------------------------------------------------------------

__device__ __forceinline__ float sp_f(float x) {
  return x > 20.0f ? x : log1pf(expf(x));
}

// Register-tiled GEMM: out[R,64] = act(in[R,K] @ W[K,64] (+ b))
// Block: 256 thr, tile 64 rows x 64 cols; thread: 4 rows x 4 cols.
// FUSE_A: epilogue gathers P[dst],P[src], writes tj over out, emits a1.
template<int K, int ACT, int BIAS, int FUSE_A>
__global__ __launch_bounds__(256) void k_gemm_rt(
    const float* __restrict__ in, const float* __restrict__ W,
    const float* __restrict__ b, float* __restrict__ out, int R,
    const float* __restrict__ P, const int* __restrict__ eidx,
    const float* __restrict__ catt, float* __restrict__ a1)
{
  constexpr int KP = (K + 3) / 4 * 4;   // k padded to x4 (zero-filled)
  constexpr int LS = KP + 4;            // ins row stride (floats, 16B-aligned)
  __shared__ __align__(16) float ins[64 * LS];
  __shared__ __align__(16) float Ws[KP * 64];
  __shared__ float atts[128];

  const int tx = threadIdx.x;
  const int b0 = blockIdx.x * 64;

  for (int i = tx; i < KP * 64; i += 256) {
    const int k = i >> 6;
    Ws[i] = (k < K) ? W[i] : 0.0f;      // W row-major [K][64]; pad rows zero
  }
  if (FUSE_A) { if (tx < 128) atts[tx] = catt[tx]; }
  for (int i = tx; i < 64 * (KP / 4); i += 256) {
    const int row = i / (KP / 4);
    const int k4 = i % (KP / 4);
    long r = b0 + row; if (r >= R) r = R - 1;   // clamp: values unused
    float4 v;
    if (K % 4 == 0) {
      v = *(const float4*)&in[r * K + k4 * 4];
    } else {
      float t[4];
      #pragma unroll
      for (int j = 0; j < 4; ++j) {
        const int k = k4 * 4 + j;
        t[j] = (k < K) ? in[r * (long)K + k] : 0.0f;
      }
      v = make_float4(t[0], t[1], t[2], t[3]);
    }
    *(float4*)&ins[row * LS + k4 * 4] = v;
  }
  __syncthreads();

  const int lr0 = ((tx >> 6) << 4) + (((tx >> 4) & 3) << 2);  // local row base
  const int c0 = (tx & 15) << 2;                               // col base
  float acc[4][4];
  #pragma unroll
  for (int i = 0; i < 4; ++i)
    #pragma unroll
    for (int j = 0; j < 4; ++j) acc[i][j] = 0.0f;

  #pragma unroll 4
  for (int k4 = 0; k4 < KP / 4; ++k4) {
    float4 w[4], a[4];
    #pragma unroll
    for (int kk = 0; kk < 4; ++kk)
      w[kk] = *(const float4*)&Ws[(k4 * 4 + kk) * 64 + c0];
    #pragma unroll
    for (int ri = 0; ri < 4; ++ri)
      a[ri] = *(const float4*)&ins[(lr0 + ri) * LS + k4 * 4];
    #pragma unroll
    for (int ri = 0; ri < 4; ++ri) {
      const float* av = (const float*)&a[ri];
      #pragma unroll
      for (int kk = 0; kk < 4; ++kk) {
        acc[ri][0] = fmaf(av[kk], w[kk].x, acc[ri][0]);
        acc[ri][1] = fmaf(av[kk], w[kk].y, acc[ri][1]);
        acc[ri][2] = fmaf(av[kk], w[kk].z, acc[ri][2]);
        acc[ri][3] = fmaf(av[kk], w[kk].w, acc[ri][3]);
      }
    }
  }

  if (!FUSE_A) {
    float4 bias = make_float4(0.f, 0.f, 0.f, 0.f);
    if (BIAS) bias = *(const float4*)&b[c0];
    #pragma unroll
    for (int ri = 0; ri < 4; ++ri) {
      const long r = b0 + lr0 + ri;
      if (r >= R) continue;
      float4 v;
      v.x = acc[ri][0] + bias.x; v.y = acc[ri][1] + bias.y;
      v.z = acc[ri][2] + bias.z; v.w = acc[ri][3] + bias.w;
      if (ACT == 1) {
        v.x = v.x >= 0.f ? v.x : 0.2f * v.x;  v.y = v.y >= 0.f ? v.y : 0.2f * v.y;
        v.z = v.z >= 0.f ? v.z : 0.2f * v.z;  v.w = v.w >= 0.f ? v.w : 0.2f * v.w;
      }
      *(float4*)&out[r * 64 + c0] = v;
    }
  } else {
    // epilogue: ti/tj, write tj over out, attention logit a1
    #pragma unroll
    for (int ri = 0; ri < 4; ++ri) {
      const long e = b0 + lr0 + ri;
      float part = 0.0f;
      if (e < R) {
        const int s = eidx[e];
        const int d = eidx[(long)R + e];
        const float4 Pd = *(const float4*)&P[(long)d * 64 + c0];
        const float4 Ps = *(const float4*)&P[(long)s * 64 + c0];
        float tj[4];
        const float ti0 = sp_f(Pd.x + acc[ri][0]);
        const float ti1 = sp_f(Pd.y + acc[ri][1]);
        const float ti2 = sp_f(Pd.z + acc[ri][2]);
        const float ti3 = sp_f(Pd.w + acc[ri][3]);
        tj[0] = sp_f(Ps.x + acc[ri][0]);
        tj[1] = sp_f(Ps.y + acc[ri][1]);
        tj[2] = sp_f(Ps.z + acc[ri][2]);
        tj[3] = sp_f(Ps.w + acc[ri][3]);
        *(float4*)&out[e * 64 + c0] = make_float4(tj[0], tj[1], tj[2], tj[3]);
        part = ti0 * atts[c0] + ti1 * atts[c0 + 1] + ti2 * atts[c0 + 2] + ti3 * atts[c0 + 3]
             + tj[0] * atts[64 + c0] + tj[1] * atts[64 + c0 + 1]
             + tj[2] * atts[64 + c0 + 2] + tj[3] * atts[64 + c0 + 3];
      }
      #pragma unroll
      for (int off = 8; off; off >>= 1) part += __shfl_xor(part, off);
      if ((tx & 15) == 0 && e < R) a1[e] = sp_f(part);
    }
  }
}

// pass B: agg[dst] += tj * (ew[e]/nsum[dst])
__global__ __launch_bounds__(256) void k_edgeB(
    const float* __restrict__ M, const int* __restrict__ dstp,
    const float* __restrict__ ew, const float* __restrict__ nsum,
    float* __restrict__ agg, int E)
{
  const int t = threadIdx.x & 63;
  const int wid = threadIdx.x >> 6;
  const long step = (long)gridDim.x * 4;
  for (long e = (long)blockIdx.x * 4 + wid; e < E; e += step) {
    const int d = dstp[e];
    const float w = ew[e] / nsum[d];
    const float tj = M[e * 64 + t];
    atomicAdd(&agg[(long)d * 64 + t], tj * w);
  }
}

// sum & sumsq of a[0..n) into stats[0..1] (pre-zeroed)
__global__ __launch_bounds__(256) void k_reduce1(
    const float* __restrict__ a, int n, float* __restrict__ stats)
{
  float s = 0.f, s2 = 0.f;
  for (int i = blockIdx.x * 256 + threadIdx.x; i < n; i += gridDim.x * 256) {
    const float v = a[i];
    s += v; s2 += v * v;
  }
  #pragma unroll
  for (int off = 32; off; off >>= 1) { s += __shfl_xor(s, off); s2 += __shfl_xor(s2, off); }
  __shared__ float ls[4], ls2[4];
  const int wid = threadIdx.x >> 6;
  if ((threadIdx.x & 63) == 0) { ls[wid] = s; ls2[wid] = s2; }
  __syncthreads();
  if (threadIdx.x == 0) {
    atomicAdd(&stats[0], ls[0] + ls[1] + ls[2] + ls[3]);
    atomicAdd(&stats[1], ls2[0] + ls2[1] + ls2[2] + ls2[3]);
  }
}

// alpha2 = sp((a1 - mean)*rsqrt(var+eps)); scatter-max to nmax[dst] (values > 0)
__global__ __launch_bounds__(256) void k_alpha_bn(
    float* __restrict__ aE, const int* __restrict__ dstp, int E,
    const float* __restrict__ stats, float invE, unsigned int* __restrict__ nmax)
{
  const float mean = stats[0] * invE;
  const float var = stats[1] * invE - mean * mean;
  const float scl = rsqrtf(var + 1e-5f);
  for (int i = blockIdx.x * 256 + threadIdx.x; i < E; i += gridDim.x * 256) {
    const float v = sp_f((aE[i] - mean) * scl);
    aE[i] = v;
    atomicMax(&nmax[dstp[i]], __float_as_uint(v));  // v > 0: uint cmp == float cmp
  }
}

// ew = exp(alpha2 - max[dst]); scatter-add to nsum[dst]
__global__ __launch_bounds__(256) void k_expsum(
    float* __restrict__ aE, const int* __restrict__ dstp, int E,
    const unsigned int* __restrict__ nmax, float* __restrict__ nsum)
{
  for (int i = blockIdx.x * 256 + threadIdx.x; i < E; i += gridDim.x * 256) {
    const float mx = __uint_as_float(nmax[dstp[i]]);
    const float w = expf(aE[i] - mx);
    aE[i] = w;
    atomicAdd(&nsum[dstp[i]], w);
  }
}

// per-column sum & sumsq of agg[N,64] into cs[0..63], cs[64..127] (pre-zeroed)
__global__ __launch_bounds__(256) void k_colstats(
    const float* __restrict__ agg, int N, float* __restrict__ cs)
{
  const int c = threadIdx.x & 63;
  const int r = threadIdx.x >> 6;
  float s = 0.f, s2 = 0.f;
  for (long n = (long)blockIdx.x * 4 + r; n < N; n += (long)gridDim.x * 4) {
    const float v = agg[n * 64 + c];
    s += v; s2 += v * v;
  }
  __shared__ float b1[256], b2[256];
  b1[threadIdx.x] = s; b2[threadIdx.x] = s2;
  __syncthreads();
  if (threadIdx.x < 64) {
    atomicAdd(&cs[c], b1[c] + b1[64 + c] + b1[128 + c] + b1[192 + c]);
    atomicAdd(&cs[64 + c], b2[c] + b2[64 + c] + b2[128 + c] + b2[192 + c]);
  }
}

// h = sp((agg - mean_c) * rsqrt(var_c + eps))
__global__ __launch_bounds__(256) void k_hnew(
    const float* __restrict__ agg, const float* __restrict__ cs,
    float invN, float* __restrict__ h, int N)
{
  const long total = (long)N * 64;
  for (long i = (long)blockIdx.x * 256 + threadIdx.x; i < total; i += (long)gridDim.x * 256) {
    const int c = (int)(i & 63);
    const float mean = cs[c] * invN;
    const float var = cs[64 + c] * invN - mean * mean;
    h[i] = sp_f((agg[i] - mean) * rsqrtf(var + 1e-5f));
  }
}

// composition attention score a[n] = sp(concat(h,gf)@Wc + bc) @ attW + attb
__global__ __launch_bounds__(256) void k_comp(
    const float* __restrict__ h, const float* __restrict__ gf,
    const int* __restrict__ batch, const float* __restrict__ Wc,
    const float* __restrict__ bc, const float* __restrict__ aw,
    const float* __restrict__ ab, float* __restrict__ aN, int N)
{
  __shared__ float Wcs[167 * 32];
  __shared__ float aws[32];
  __shared__ float bcs[32];
  for (int i = threadIdx.x; i < 167 * 32; i += 256) Wcs[i] = Wc[i];
  if (threadIdx.x < 32) { aws[threadIdx.x] = aw[threadIdx.x]; bcs[threadIdx.x] = bc[threadIdx.x]; }
  __syncthreads();
  const int t = threadIdx.x & 63;
  const int wid = threadIdx.x >> 6;
  const int col = t & 31;
  const float ab0 = ab[0];
  const int step = gridDim.x * 4;
  for (int n = blockIdx.x * 4 + wid; n < N; n += step) {
    const int g = batch[n];
    const float hq = h[(long)n * 64 + t];
    const float g1 = gf[(long)g * 103 + t];
    const float g2 = (t < 39) ? gf[(long)g * 103 + 64 + t] : 0.f;
    float acc = bcs[col];
    #pragma unroll 8
    for (int k = 0; k < 64; ++k) acc = fmaf(__shfl(hq, k), Wcs[k * 32 + col], acc);
    #pragma unroll 8
    for (int k = 0; k < 64; ++k) acc = fmaf(__shfl(g1, k), Wcs[(64 + k) * 32 + col], acc);
    #pragma unroll
    for (int k = 0; k < 39; ++k) acc = fmaf(__shfl(g2, k), Wcs[(128 + k) * 32 + col], acc);
    float val = sp_f(acc) * aws[col];
    #pragma unroll
    for (int off = 16; off; off >>= 1) val += __shfl_xor(val, off);
    if (t == 0) aN[n] = val + ab0;
  }
}

// one 64-thread block per graph: seg-softmax over sorted batch + pool + fc
__global__ __launch_bounds__(64) void k_pool(
    const float* __restrict__ h, const float* __restrict__ aN,
    const int* __restrict__ batch, const float* __restrict__ fcW,
    const float* __restrict__ fcb, float* __restrict__ out, int N, int G)
{
  const int g = blockIdx.x;
  const int t = threadIdx.x;
  int lo = 0, hi = N;
  while (lo < hi) { int mid = (lo + hi) >> 1; if (batch[mid] < g) lo = mid + 1; else hi = mid; }
  const int s = lo;
  hi = N;
  while (lo < hi) { int mid = (lo + hi) >> 1; if (batch[mid] < g + 1) lo = mid + 1; else hi = mid; }
  const int e2 = lo;
  if (s >= e2) { if (t == 0) out[g] = fcb[0]; return; }
  float mx = -1e30f;
  for (int i = s + t; i < e2; i += 64) mx = fmaxf(mx, aN[i]);
  #pragma unroll
  for (int off = 32; off; off >>= 1) mx = fmaxf(mx, __shfl_xor(mx, off));
  float se = 0.f;
  for (int i = s + t; i < e2; i += 64) se += expf(aN[i] - mx);
  #pragma unroll
  for (int off = 32; off; off >>= 1) se += __shfl_xor(se, off);
  float acc = 0.f;
  for (int n = s; n < e2; ++n) {
    const float w = expf(aN[n] - mx);
    acc = fmaf(h[(long)n * 64 + t], w, acc);
  }
  float part = (acc / se) * fcW[t];
  #pragma unroll
  for (int off = 32; off; off >>= 1) part += __shfl_xor(part, off);
  if (t == 0) out[g] = part + fcb[0];
}

extern "C" void kernel_launch(void* const* d_in, const int* in_sizes, int n_in,
                              void* d_out, int out_size, void* d_ws, size_t ws_size,
                              hipStream_t stream)
{
  const float* x     = (const float*)d_in[0];
  const int*   eidx  = (const int*)  d_in[1];
  const float* eattr = (const float*)d_in[2];
  const int*   batch = (const int*)  d_in[3];
  const float* gfeat = (const float*)d_in[4];
  const float* embnW = (const float*)d_in[5];
  const float* embnb = (const float*)d_in[6];
  const float* embeW = (const float*)d_in[7];
  const float* embeb = (const float*)d_in[8];
  const float* convW = (const float*)d_in[9];
  const float* convA = (const float*)d_in[10];
  // d_in[11] = conv_bias: cancels exactly in training-mode BatchNorm
  const float* compW = (const float*)d_in[12];
  const float* compb = (const float*)d_in[13];
  const float* attW  = (const float*)d_in[14];
  const float* attb  = (const float*)d_in[15];
  const float* fcW   = (const float*)d_in[16];
  const float* fcb   = (const float*)d_in[17];
  float* out = (float*)d_out;

  const int N = in_sizes[0] / 92;
  const int E = in_sizes[1] / 2;
  const int G = in_sizes[4] / 103;

  // workspace layout (fp32, ~233 MB; ws_size >= this proven in round 2)
  float* h     = (float*)d_ws;                    // N*64
  float* Pagg  = h + (size_t)N * 64;              // N*64: P (pass A), then agg
  float* aE    = Pagg + (size_t)N * 64;           // E
  float* stats = aE + E;                          // 256
  unsigned int* nmax = (unsigned int*)(stats + 256);  // N
  float* nsum  = stats + 256 + (size_t)N;         // N
  float* aN    = stats + 256 + 2 * (size_t)N;     // N
  float* ea    = stats + 256 + 3 * (size_t)N;     // E*64
  float* M     = ea + (size_t)E * 64;             // E*64: M, then tj (in place)

  const int gE64 = (E + 63) / 64;
  const int gN64 = (N + 63) / 64;

  k_gemm_rt<92, 0, 1, 0><<<gN64, 256, 0, stream>>>(x, embnW, embnb, h, N,
                                                   nullptr, nullptr, nullptr, nullptr);
  k_gemm_rt<41, 1, 1, 0><<<gE64, 256, 0, stream>>>(eattr, embeW, embeb, ea, E,
                                                   nullptr, nullptr, nullptr, nullptr);

  for (int l = 0; l < 3; ++l) {
    const float* Wl = convW + (size_t)l * 128 * 64;
    const float* Al = convA + (size_t)l * 128;
    k_gemm_rt<64, 0, 0, 0><<<gN64, 256, 0, stream>>>(h, Wl, nullptr, Pagg, N,
                                                     nullptr, nullptr, nullptr, nullptr);
    k_gemm_rt<64, 0, 0, 1><<<gE64, 256, 0, stream>>>(ea, Wl + 64 * 64, nullptr, M, E,
                                                     Pagg, eidx, Al, aE);
    hipMemsetAsync(stats, 0, (256 + 2 * (size_t)N) * sizeof(float), stream);
    hipMemsetAsync(Pagg, 0, (size_t)N * 64 * sizeof(float), stream);
    k_reduce1<<<1024, 256, 0, stream>>>(aE, E, stats);
    k_alpha_bn<<<2048, 256, 0, stream>>>(aE, eidx + E, E, stats, 1.0f / (float)E, nmax);
    k_expsum<<<2048, 256, 0, stream>>>(aE, eidx + E, E, nmax, nsum);
    k_edgeB<<<(E + 3) / 4, 256, 0, stream>>>(M, eidx + E, aE, nsum, Pagg, E);
    k_colstats<<<1024, 256, 0, stream>>>(Pagg, N, stats + 64);
    k_hnew<<<2048, 256, 0, stream>>>(Pagg, stats + 64, 1.0f / (float)N, h, N);
  }

  k_comp<<<gN64, 256, 0, stream>>>(h, gfeat, batch, compW, compb, attW, attb, aN, N);
  k_pool<<<G, 64, 0, stream>>>(h, aN, batch, fcW, fcb, out, N, G);

  (void)n_in; (void)out_size; (void)ws_size;
}

// Round 4
// 1352.930 us; speedup vs baseline: 5.6818x; 1.2211x over previous
//
#include <hip/hip_runtime.h>
#include <hip/hip_bf16.h>
#include <math.h>

// ---------------------------------------------------------------------------
// GATGNN forward, fp32 (ws_size >= 233 MB proven in round 2; this uses ~220MB).
//   h = x@Wn + bn; ea = leaky_relu(eattr@We + be)
//   per layer:
//     P = h@Wtop                       (register-tiled GEMM)
//     fused: M = ea@Wbot; ti=sp(P[dst]+M), tj=sp(P[src]+M); M<-tj;
//            a1 = sp(dot(ti,att_i)+dot(tj,att_j)); stats(a1) via atomics
//     ew = exp(sp(BN(a1)))  (no max-subtract: alpha in (0,~6], exp <= ~403)
//     agg[dst] += tj*ew;  node-side /nsum folded into BN stage
//     h = sp(BN(agg/nsum))             (conv_bias cancels in BN)
//   comp attention + seg-softmax over sorted batch + pool + fc
// Fast softplus: __logf/__expf -> v_log_f32/v_exp_f32 (err ~1e-6 << 5e-2 tol)
// ---------------------------------------------------------------------------

__device__ __forceinline__ float sp_f(float x) {
  return x > 20.0f ? x : __logf(1.0f + __expf(x));
}

// Register-tiled GEMM: out[R,64] = act(in[R,K] @ W[K,64] (+ b))
// Block: 256 thr, tile 64 rows x 64 cols; thread: 4 rows x 4 cols.
// FUSE_A: epilogue gathers P[dst],P[src], writes tj over out, emits a1 and
//         accumulates sum/sumsq of a1 into stats[0..1] (pre-zeroed).
template<int K, int ACT, int BIAS, int FUSE_A>
__global__ __launch_bounds__(256) void k_gemm_rt(
    const float* __restrict__ in, const float* __restrict__ W,
    const float* __restrict__ b, float* __restrict__ out, int R,
    const float* __restrict__ P, const int* __restrict__ eidx,
    const float* __restrict__ catt, float* __restrict__ a1,
    float* __restrict__ stats)
{
  constexpr int KP = (K + 3) / 4 * 4;   // k padded to x4 (zero-filled)
  constexpr int LS = KP + 4;            // ins row stride (floats, 16B-aligned)
  __shared__ __align__(16) float ins[64 * LS];
  __shared__ __align__(16) float Ws[KP * 64];
  __shared__ float atts[128];
  __shared__ float ssum[4], ssq[4];

  const int tx = threadIdx.x;
  const int b0 = blockIdx.x * 64;

  for (int i = tx; i < KP * 64; i += 256) {
    const int k = i >> 6;
    Ws[i] = (k < K) ? W[i] : 0.0f;      // W row-major [K][64]; pad rows zero
  }
  if (FUSE_A) { if (tx < 128) atts[tx] = catt[tx]; }
  for (int i = tx; i < 64 * (KP / 4); i += 256) {
    const int row = i / (KP / 4);
    const int k4 = i % (KP / 4);
    long r = b0 + row; if (r >= R) r = R - 1;   // clamp: values unused
    float4 v;
    if (K % 4 == 0) {
      v = *(const float4*)&in[r * K + k4 * 4];
    } else {
      float t[4];
      #pragma unroll
      for (int j = 0; j < 4; ++j) {
        const int k = k4 * 4 + j;
        t[j] = (k < K) ? in[r * (long)K + k] : 0.0f;
      }
      v = make_float4(t[0], t[1], t[2], t[3]);
    }
    *(float4*)&ins[row * LS + k4 * 4] = v;
  }
  __syncthreads();

  const int lr0 = ((tx >> 6) << 4) + (((tx >> 4) & 3) << 2);  // local row base
  const int c0 = (tx & 15) << 2;                               // col base
  float acc[4][4];
  #pragma unroll
  for (int i = 0; i < 4; ++i)
    #pragma unroll
    for (int j = 0; j < 4; ++j) acc[i][j] = 0.0f;

  #pragma unroll 4
  for (int k4 = 0; k4 < KP / 4; ++k4) {
    float4 w[4], a[4];
    #pragma unroll
    for (int kk = 0; kk < 4; ++kk)
      w[kk] = *(const float4*)&Ws[(k4 * 4 + kk) * 64 + c0];
    #pragma unroll
    for (int ri = 0; ri < 4; ++ri)
      a[ri] = *(const float4*)&ins[(lr0 + ri) * LS + k4 * 4];
    #pragma unroll
    for (int ri = 0; ri < 4; ++ri) {
      const float* av = (const float*)&a[ri];
      #pragma unroll
      for (int kk = 0; kk < 4; ++kk) {
        acc[ri][0] = fmaf(av[kk], w[kk].x, acc[ri][0]);
        acc[ri][1] = fmaf(av[kk], w[kk].y, acc[ri][1]);
        acc[ri][2] = fmaf(av[kk], w[kk].z, acc[ri][2]);
        acc[ri][3] = fmaf(av[kk], w[kk].w, acc[ri][3]);
      }
    }
  }

  if (!FUSE_A) {
    float4 bias = make_float4(0.f, 0.f, 0.f, 0.f);
    if (BIAS) bias = *(const float4*)&b[c0];
    #pragma unroll
    for (int ri = 0; ri < 4; ++ri) {
      const long r = b0 + lr0 + ri;
      if (r >= R) continue;
      float4 v;
      v.x = acc[ri][0] + bias.x; v.y = acc[ri][1] + bias.y;
      v.z = acc[ri][2] + bias.z; v.w = acc[ri][3] + bias.w;
      if (ACT == 1) {
        v.x = v.x >= 0.f ? v.x : 0.2f * v.x;  v.y = v.y >= 0.f ? v.y : 0.2f * v.y;
        v.z = v.z >= 0.f ? v.z : 0.2f * v.z;  v.w = v.w >= 0.f ? v.w : 0.2f * v.w;
      }
      *(float4*)&out[r * 64 + c0] = v;
    }
  } else {
    // epilogue: ti/tj, write tj over out, attention logit a1, a1 stats
    float s1 = 0.f, s2 = 0.f;
    #pragma unroll
    for (int ri = 0; ri < 4; ++ri) {
      const long e = b0 + lr0 + ri;
      float part = 0.0f;
      if (e < R) {
        const int s = eidx[e];
        const int d = eidx[(long)R + e];
        const float4 Pd = *(const float4*)&P[(long)d * 64 + c0];
        const float4 Ps = *(const float4*)&P[(long)s * 64 + c0];
        float tj[4];
        const float ti0 = sp_f(Pd.x + acc[ri][0]);
        const float ti1 = sp_f(Pd.y + acc[ri][1]);
        const float ti2 = sp_f(Pd.z + acc[ri][2]);
        const float ti3 = sp_f(Pd.w + acc[ri][3]);
        tj[0] = sp_f(Ps.x + acc[ri][0]);
        tj[1] = sp_f(Ps.y + acc[ri][1]);
        tj[2] = sp_f(Ps.z + acc[ri][2]);
        tj[3] = sp_f(Ps.w + acc[ri][3]);
        *(float4*)&out[e * 64 + c0] = make_float4(tj[0], tj[1], tj[2], tj[3]);
        part = ti0 * atts[c0] + ti1 * atts[c0 + 1] + ti2 * atts[c0 + 2] + ti3 * atts[c0 + 3]
             + tj[0] * atts[64 + c0] + tj[1] * atts[64 + c0 + 1]
             + tj[2] * atts[64 + c0 + 2] + tj[3] * atts[64 + c0 + 3];
      }
      #pragma unroll
      for (int off = 8; off; off >>= 1) part += __shfl_xor(part, off);
      if ((tx & 15) == 0 && e < R) {
        const float v = sp_f(part);
        a1[e] = v;
        s1 += v; s2 += v * v;
      }
    }
    s1 += __shfl_xor(s1, 16); s2 += __shfl_xor(s2, 16);
    s1 += __shfl_xor(s1, 32); s2 += __shfl_xor(s2, 32);
    if ((tx & 63) == 0) { ssum[tx >> 6] = s1; ssq[tx >> 6] = s2; }
    __syncthreads();
    if (tx == 0) {
      atomicAdd(&stats[0], ssum[0] + ssum[1] + ssum[2] + ssum[3]);
      atomicAdd(&stats[1], ssq[0] + ssq[1] + ssq[2] + ssq[3]);
    }
  }
}

// ew = exp(sp((a1-mean)*rsqrt(var+eps))); scatter-add ew to nsum[dst]
__global__ __launch_bounds__(256) void k_expsum_bn(
    float* __restrict__ aE, const int* __restrict__ dstp, int E,
    const float* __restrict__ stats, float invE, float* __restrict__ nsum)
{
  const float mean = stats[0] * invE;
  const float var = stats[1] * invE - mean * mean;
  const float scl = rsqrtf(var + 1e-5f);
  for (int i = blockIdx.x * 256 + threadIdx.x; i < E; i += gridDim.x * 256) {
    const float w = __expf(sp_f((aE[i] - mean) * scl));
    aE[i] = w;
    atomicAdd(&nsum[dstp[i]], w);
  }
}

// pass B: agg[dst] += tj * ew[e]   (normalization by nsum done node-side)
__global__ __launch_bounds__(256) void k_edgeB(
    const float* __restrict__ M, const int* __restrict__ dstp,
    const float* __restrict__ ew, float* __restrict__ agg, int E)
{
  const int t = threadIdx.x & 63;
  const int wid = threadIdx.x >> 6;
  const long step = (long)gridDim.x * 4;
  for (long e = (long)blockIdx.x * 4 + wid; e < E; e += step) {
    const int d = dstp[e];
    const float w = ew[e];
    const float tj = M[e * 64 + t];
    atomicAdd(&agg[(long)d * 64 + t], tj * w);
  }
}

// per-column sum & sumsq of agg[N,64]/nsum[n] into cs[0..63],[64..127] (pre-zeroed)
__global__ __launch_bounds__(256) void k_colstats(
    const float* __restrict__ agg, const float* __restrict__ nsum,
    int N, float* __restrict__ cs)
{
  const int c = threadIdx.x & 63;
  const int r = threadIdx.x >> 6;
  float s = 0.f, s2 = 0.f;
  for (long n = (long)blockIdx.x * 4 + r; n < N; n += (long)gridDim.x * 4) {
    const float sn = nsum[n];
    const float scale = sn > 0.f ? 1.0f / sn : 0.0f;   // isolated nodes: agg=0
    const float v = agg[n * 64 + c] * scale;
    s += v; s2 += v * v;
  }
  __shared__ float b1[256], b2[256];
  b1[threadIdx.x] = s; b2[threadIdx.x] = s2;
  __syncthreads();
  if (threadIdx.x < 64) {
    atomicAdd(&cs[c], b1[c] + b1[64 + c] + b1[128 + c] + b1[192 + c]);
    atomicAdd(&cs[64 + c], b2[c] + b2[64 + c] + b2[128 + c] + b2[192 + c]);
  }
}

// h = sp((agg/nsum - mean_c) * rsqrt(var_c + eps))
__global__ __launch_bounds__(256) void k_hnew(
    const float* __restrict__ agg, const float* __restrict__ nsum,
    const float* __restrict__ cs, float invN, float* __restrict__ h, int N)
{
  const int c = threadIdx.x & 63;
  const int r = threadIdx.x >> 6;
  const float mean = cs[c] * invN;
  const float var = cs[64 + c] * invN - mean * mean;
  const float scl = rsqrtf(var + 1e-5f);
  for (long n = (long)blockIdx.x * 4 + r; n < N; n += (long)gridDim.x * 4) {
    const float sn = nsum[n];
    const float scale = sn > 0.f ? 1.0f / sn : 0.0f;
    h[n * 64 + c] = sp_f((agg[n * 64 + c] * scale - mean) * scl);
  }
}

// composition attention score a[n] = sp(concat(h,gf)@Wc + bc) @ attW + attb
__global__ __launch_bounds__(256) void k_comp(
    const float* __restrict__ h, const float* __restrict__ gf,
    const int* __restrict__ batch, const float* __restrict__ Wc,
    const float* __restrict__ bc, const float* __restrict__ aw,
    const float* __restrict__ ab, float* __restrict__ aN, int N)
{
  __shared__ float Wcs[167 * 32];
  __shared__ float aws[32];
  __shared__ float bcs[32];
  for (int i = threadIdx.x; i < 167 * 32; i += 256) Wcs[i] = Wc[i];
  if (threadIdx.x < 32) { aws[threadIdx.x] = aw[threadIdx.x]; bcs[threadIdx.x] = bc[threadIdx.x]; }
  __syncthreads();
  const int t = threadIdx.x & 63;
  const int wid = threadIdx.x >> 6;
  const int col = t & 31;
  const float ab0 = ab[0];
  const int step = gridDim.x * 4;
  for (int n = blockIdx.x * 4 + wid; n < N; n += step) {
    const int g = batch[n];
    const float hq = h[(long)n * 64 + t];
    const float g1 = gf[(long)g * 103 + t];
    const float g2 = (t < 39) ? gf[(long)g * 103 + 64 + t] : 0.f;
    float acc = bcs[col];
    #pragma unroll 8
    for (int k = 0; k < 64; ++k) acc = fmaf(__shfl(hq, k), Wcs[k * 32 + col], acc);
    #pragma unroll 8
    for (int k = 0; k < 64; ++k) acc = fmaf(__shfl(g1, k), Wcs[(64 + k) * 32 + col], acc);
    #pragma unroll
    for (int k = 0; k < 39; ++k) acc = fmaf(__shfl(g2, k), Wcs[(128 + k) * 32 + col], acc);
    float val = sp_f(acc) * aws[col];
    #pragma unroll
    for (int off = 16; off; off >>= 1) val += __shfl_xor(val, off);
    if (t == 0) aN[n] = val + ab0;
  }
}

// one 64-thread block per graph: seg-softmax over sorted batch + pool + fc
__global__ __launch_bounds__(64) void k_pool(
    const float* __restrict__ h, const float* __restrict__ aN,
    const int* __restrict__ batch, const float* __restrict__ fcW,
    const float* __restrict__ fcb, float* __restrict__ out, int N, int G)
{
  const int g = blockIdx.x;
  const int t = threadIdx.x;
  int lo = 0, hi = N;
  while (lo < hi) { int mid = (lo + hi) >> 1; if (batch[mid] < g) lo = mid + 1; else hi = mid; }
  const int s = lo;
  hi = N;
  while (lo < hi) { int mid = (lo + hi) >> 1; if (batch[mid] < g + 1) lo = mid + 1; else hi = mid; }
  const int e2 = lo;
  if (s >= e2) { if (t == 0) out[g] = fcb[0]; return; }
  float mx = -1e30f;
  for (int i = s + t; i < e2; i += 64) mx = fmaxf(mx, aN[i]);
  #pragma unroll
  for (int off = 32; off; off >>= 1) mx = fmaxf(mx, __shfl_xor(mx, off));
  float se = 0.f;
  for (int i = s + t; i < e2; i += 64) se += __expf(aN[i] - mx);
  #pragma unroll
  for (int off = 32; off; off >>= 1) se += __shfl_xor(se, off);
  float acc = 0.f;
  for (int n = s; n < e2; ++n) {
    const float w = __expf(aN[n] - mx);
    acc = fmaf(h[(long)n * 64 + t], w, acc);
  }
  float part = (acc / se) * fcW[t];
  #pragma unroll
  for (int off = 32; off; off >>= 1) part += __shfl_xor(part, off);
  if (t == 0) out[g] = part + fcb[0];
}

extern "C" void kernel_launch(void* const* d_in, const int* in_sizes, int n_in,
                              void* d_out, int out_size, void* d_ws, size_t ws_size,
                              hipStream_t stream)
{
  const float* x     = (const float*)d_in[0];
  const int*   eidx  = (const int*)  d_in[1];
  const float* eattr = (const float*)d_in[2];
  const int*   batch = (const int*)  d_in[3];
  const float* gfeat = (const float*)d_in[4];
  const float* embnW = (const float*)d_in[5];
  const float* embnb = (const float*)d_in[6];
  const float* embeW = (const float*)d_in[7];
  const float* embeb = (const float*)d_in[8];
  const float* convW = (const float*)d_in[9];
  const float* convA = (const float*)d_in[10];
  // d_in[11] = conv_bias: cancels exactly in training-mode BatchNorm
  const float* compW = (const float*)d_in[12];
  const float* compb = (const float*)d_in[13];
  const float* attW  = (const float*)d_in[14];
  const float* attb  = (const float*)d_in[15];
  const float* fcW   = (const float*)d_in[16];
  const float* fcb   = (const float*)d_in[17];
  float* out = (float*)d_out;

  const int N = in_sizes[0] / 92;
  const int E = in_sizes[1] / 2;
  const int G = in_sizes[4] / 103;

  // workspace layout (fp32, ~220 MB)
  float* h     = (float*)d_ws;                    // N*64
  float* Pagg  = h + (size_t)N * 64;              // N*64: P (pass A), then agg
  float* aE    = Pagg + (size_t)N * 64;           // E   (a1 -> ew, in place)
  float* stats = aE + E;                          // 256: [0..1] BN-E, [64..191] cs
  float* nsum  = stats + 256;                     // N
  float* aN    = nsum + (size_t)N;                // N
  float* ea    = aN + (size_t)N;                  // E*64
  float* M     = ea + (size_t)E * 64;             // E*64: M, then tj (in place)

  const int gE64 = (E + 63) / 64;
  const int gN64 = (N + 63) / 64;

  k_gemm_rt<92, 0, 1, 0><<<gN64, 256, 0, stream>>>(x, embnW, embnb, h, N,
      nullptr, nullptr, nullptr, nullptr, nullptr);
  k_gemm_rt<41, 1, 1, 0><<<gE64, 256, 0, stream>>>(eattr, embeW, embeb, ea, E,
      nullptr, nullptr, nullptr, nullptr, nullptr);

  for (int l = 0; l < 3; ++l) {
    const float* Wl = convW + (size_t)l * 128 * 64;
    const float* Al = convA + (size_t)l * 128;
    hipMemsetAsync(stats, 0, (256 + (size_t)N) * sizeof(float), stream);
    k_gemm_rt<64, 0, 0, 0><<<gN64, 256, 0, stream>>>(h, Wl, nullptr, Pagg, N,
        nullptr, nullptr, nullptr, nullptr, nullptr);
    k_gemm_rt<64, 0, 0, 1><<<gE64, 256, 0, stream>>>(ea, Wl + 64 * 64, nullptr, M, E,
        Pagg, eidx, Al, aE, stats);
    hipMemsetAsync(Pagg, 0, (size_t)N * 64 * sizeof(float), stream);
    k_expsum_bn<<<2048, 256, 0, stream>>>(aE, eidx + E, E, stats, 1.0f / (float)E, nsum);
    k_edgeB<<<(E + 3) / 4, 256, 0, stream>>>(M, eidx + E, aE, Pagg, E);
    k_colstats<<<1024, 256, 0, stream>>>(Pagg, nsum, N, stats + 64);
    k_hnew<<<2048, 256, 0, stream>>>(Pagg, nsum, stats + 64, 1.0f / (float)N, h, N);
  }

  k_comp<<<gN64, 256, 0, stream>>>(h, gfeat, batch, compW, compb, attW, attb, aN, N);
  k_pool<<<G, 64, 0, stream>>>(h, aN, batch, fcW, fcb, out, N, G);

  (void)n_in; (void)out_size; (void)ws_size;
}